// Round 3
// baseline (475.121 us; speedup 1.0000x reference)
//
#include <hip/hip_runtime.h>

// Native 16B vector type (HIP_vector_type structs are rejected by the
// nontemporal builtins; ext_vector_type lowers to the same dwordx4).
typedef float float4n __attribute__((ext_vector_type(4)));

// Problem config (fixed by the reference's setup_inputs)
constexpr int B     = 8;      // batch
constexpr int BS    = 16;     // tokens per cache block
constexpr int MAXB  = 128;    // max blocks per seq
constexpr int H     = 8;      // kv heads
constexpr int D     = 128;    // head dim
constexpr int TOTAL = 2048;   // physical blocks (= free_blocks size)

constexpr int C4   = TOTAL * H * BS * D / 4; // float4 per cache: 8,388,608
constexpr int PB4  = H * BS * D / 4;         // float4 per block: 4096
constexpr int PT4  = H * D / 4;              // float4 per token in states: 256
constexpr int PO4  = D / 4;                  // float4 per token-head: 32

// ---------------------------------------------------------------------------
// One workgroup per physical cache block. The wg first resolves whether its
// block receives new tokens (parallel search over the <=B*MAXB candidate
// allocations, mirroring the reference's cumsum tail-pop exactly), then
// streams 2 x 4096 float4 (K and V) from either the states or the old cache.
// All wide, coalesced, nontemporal.
// ---------------------------------------------------------------------------
__global__ __launch_bounds__(256) void paged_kv_kernel(
        const float4n* __restrict__ key_states,
        const float4n* __restrict__ value_states,
        const float4n* __restrict__ k_cache,
        const float4n* __restrict__ v_cache,
        const int*     __restrict__ input_len,
        const int*     __restrict__ cu_seqlens,
        const int*     __restrict__ block_tables,
        const int*     __restrict__ seq_lens,
        const int*     __restrict__ free_blocks,
        float4n*       __restrict__ out) {
    const int myblk = blockIdx.x;        // physical block id, grid == TOTAL
    const int tid   = threadIdx.x;

    // ---- resolve owner: does myblk receive new tokens? ----
    __shared__ int s_found;
    if (tid == 0) s_found = -1;
    __syncthreads();

    int cum = 0;
    #pragma unroll
    for (int b = 0; b < B; ++b) {
        const int sl  = seq_lens[b];
        const int il  = input_len[b];
        const int onb = (sl + BS - 1) >> 4;        // blocks already held
        const int nnb = (sl + il + BS - 1) >> 4;   // blocks after append
        cum += nnb - onb;
        const int st  = TOTAL - cum;               // free-list start for seq b
        const int j0  = sl >> 4;                   // first slot touched
        for (int j = j0 + tid; j < nnb; j += 256) {
            int cand;
            if (j >= onb) {
                int fi = st + (j - onb);
                fi = min(max(fi, 0), TOTAL - 1);   // reference's clip
                cand = free_blocks[fi];
            } else {
                cand = block_tables[b * MAXB + j]; // existing partial block
            }
            if (cand == myblk) s_found = (b << 20) | j;
        }
    }
    __syncthreads();
    const int m = s_found;

    const int base4 = myblk * PB4;

    if (m < 0) {
        // pure pass-through block: stream cache -> out (K and V)
        #pragma unroll 4
        for (int t = 0; t < PB4 / 256; ++t) {
            const int i4 = (t << 8) + tid;
            float4n k = __builtin_nontemporal_load(&k_cache[base4 + i4]);
            float4n v = __builtin_nontemporal_load(&v_cache[base4 + i4]);
            __builtin_nontemporal_store(k, &out[base4 + i4]);
            __builtin_nontemporal_store(v, &out[C4 + base4 + i4]);
        }
    } else {
        const int b  = m >> 20;
        const int j  = m & 0xFFFFF;
        const int sl = seq_lens[b];
        const int il = input_len[b];
        const int cu = cu_seqlens[b];
        #pragma unroll 4
        for (int t = 0; t < PB4 / 256; ++t) {
            const int i4  = (t << 8) + tid;
            const int h   = i4 >> 9;          // PH4 = 512
            const int off = (i4 >> 5) & 15;   // PO4 = 32
            const int d4  = i4 & 31;
            const int pos = j * BS + off;     // absolute position in sequence
            float4n k, v;
            if (pos >= sl && pos < sl + il) { // freshly appended token
                const int tok = cu + (pos - sl);
                const int si  = tok * PT4 + h * PO4 + d4;
                k = __builtin_nontemporal_load(&key_states[si]);
                v = __builtin_nontemporal_load(&value_states[si]);
            } else {                          // retained old contents
                k = __builtin_nontemporal_load(&k_cache[base4 + i4]);
                v = __builtin_nontemporal_load(&v_cache[base4 + i4]);
            }
            __builtin_nontemporal_store(k, &out[base4 + i4]);
            __builtin_nontemporal_store(v, &out[C4 + base4 + i4]);
        }
    }
}

extern "C" void kernel_launch(void* const* d_in, const int* in_sizes, int n_in,
                              void* d_out, int out_size, void* d_ws, size_t ws_size,
                              hipStream_t stream) {
    // setup_inputs order:
    // 0 layer_idx, 1 key_states, 2 value_states, 3 input_len, 4 cu_seqlens,
    // 5 k_cache, 6 v_cache, 7 block_tables, 8 seq_lens, 9 free_blocks
    const float* key_states   = (const float*)d_in[1];
    const float* value_states = (const float*)d_in[2];
    const int*   input_len    = (const int*)d_in[3];
    const int*   cu_seqlens   = (const int*)d_in[4];
    const float* k_cache      = (const float*)d_in[5];
    const float* v_cache      = (const float*)d_in[6];
    const int*   block_tables = (const int*)d_in[7];
    const int*   seq_lens     = (const int*)d_in[8];
    const int*   free_blocks  = (const int*)d_in[9];

    paged_kv_kernel<<<TOTAL, 256, 0, stream>>>(
        (const float4n*)key_states, (const float4n*)value_states,
        (const float4n*)k_cache, (const float4n*)v_cache,
        input_len, cu_seqlens, block_tables, seq_lens, free_blocks,
        (float4n*)d_out);
}